// Round 16
// baseline (96.035 us; speedup 1.0000x reference)
//
#include <hip/hip_runtime.h>
#include <hip/hip_bf16.h>
#include <stdint.h>

typedef float f4 __attribute__((ext_vector_type(4)));
typedef float f32x4v __attribute__((ext_vector_type(4)));
typedef float f32x16 __attribute__((ext_vector_type(16)));
typedef short bf16x8 __attribute__((ext_vector_type(8)));
typedef unsigned int u32x2 __attribute__((ext_vector_type(2)));

static constexpr int Bc = 16, Nc = 16384, DIN = 64, DOUT = 128, Mc = 4096, KNN = 16;
static constexpr long Rr = (long)Bc * Nc;        // 262144 rows
static constexpr float EPS = 1e-5f;
static constexpr int POS_OUT = Bc * Mc * 3;      // 196608 floats of pos_ds
static constexpr int GBLK = 512;                 // k_gram blocks (512 rows each)
static constexpr int PSTRIDE = 4160;             // 64 colsum + 4096 gram per partial
static constexpr int RGRP = 32;                  // reduction groups (stage 1)
static constexpr int CG_STRIDE = 8224;           // bytes per 16-chan LDS subtile (+32 pad)

__device__ __forceinline__ uint32_t cvt2(float a, float b) {
    union { __hip_bfloat162 h; uint32_t u; } c;
    c.h = __float22bfloat162_rn(make_float2(a, b));   // v_cvt_pk_bf16_f32
    return c.u;
}

// ---------------------------------------------------------------------------
// Kernel A (MFMA Gram): G = feat^T feat via mfma_f32_16x16x32_bf16 with
// ds_read_b64_tr_b16 fragments (one fragment serves as both A and B).
// Emits feat16 + colsum. 512 blocks x 512 rows. (~HBM floor since R9.)
// ---------------------------------------------------------------------------
__global__ __launch_bounds__(256) void k_gram(const float* __restrict__ feat,
                                              unsigned short* __restrict__ feat16,
                                              float* __restrict__ part)
{
    __shared__ alignas(16) char lds[4 * CG_STRIDE];   // 32896 B; reused as merge buf
    const int t = threadIdx.x;
    const int lane = t & 63;
    const int w = t >> 6;
    const long R0 = (long)blockIdx.x * 512;
    const f4* feat4 = (const f4*)feat;
    const unsigned lds_base = (unsigned)(size_t)&lds[0];

    f32x4v acc[4][4];
#pragma unroll
    for (int mi = 0; mi < 4; ++mi)
#pragma unroll
        for (int mj = 0; mj < 4; ++mj) acc[mi][mj] = (f32x4v){0.f, 0.f, 0.f, 0.f};
    f4 csum = (f4){0.f, 0.f, 0.f, 0.f};

    f4 v[16];
#pragma unroll
    for (int i = 0; i < 16; ++i)                 // preload chunk 0 (coalesced)
        v[i] = feat4[R0 * 16 + t + i * 256];

    const int c4 = t & 15;
    const int cg = c4 >> 2;

    for (int ch = 0; ch < 2; ++ch) {
        // ---- stage: bf16 to LDS subtiles + feat16 global + colsum ----
#pragma unroll
        for (int i = 0; i < 16; ++i) {
            int row = (t + i * 256) >> 4;        // 0..255
            uint2 pk = {cvt2(v[i][0], v[i][1]), cvt2(v[i][2], v[i][3])};
            csum += v[i];
            *(uint2*)(feat16 + (size_t)(R0 + ch * 256 + row) * 64 + c4 * 4) = pk;
            *(uint2*)(lds + cg * CG_STRIDE + row * 32 + (c4 & 3) * 8) = pk;
        }
        __syncthreads();
        if (ch == 0) {                           // preload chunk 1 under compute
#pragma unroll
            for (int i = 0; i < 16; ++i)
                v[i] = feat4[(R0 + 256) * 16 + t + i * 256];
        }
        // ---- compute: wave w owns K-steps 2w, 2w+1 (32 rows each) ----
#pragma unroll
        for (int s = 0; s < 2; ++s) {
            const unsigned base = lds_base + (unsigned)((w * 2 + s) * 32 * 32 + lane * 8);
            u32x2 r0[4], r1[4];
#pragma unroll
            for (int g = 0; g < 4; ++g) {
                unsigned a = base + g * CG_STRIDE;
                asm volatile("ds_read_b64_tr_b16 %0, %2 offset:0\n\t"
                             "ds_read_b64_tr_b16 %1, %2 offset:512"
                             : "=v"(r0[g]), "=v"(r1[g]) : "v"(a));
            }
            asm volatile("s_waitcnt lgkmcnt(0)" ::: "memory");
            __builtin_amdgcn_sched_barrier(0);
            bf16x8 f[4];
#pragma unroll
            for (int g = 0; g < 4; ++g) {
                union { u32x2 p[2]; bf16x8 v8; } u;
                u.p[0] = r0[g]; u.p[1] = r1[g];
                f[g] = u.v8;
            }
#pragma unroll
            for (int mi = 0; mi < 4; ++mi)
#pragma unroll
                for (int mj = 0; mj < 4; ++mj)
                    acc[mi][mj] = __builtin_amdgcn_mfma_f32_16x16x32_bf16(
                        f[mi], f[mj], acc[mi][mj], 0, 0, 0);
        }
        __syncthreads();
    }

    // ---- colsum merge ----
    float* fbuf = (float*)lds;
    ((f4*)fbuf)[t] = csum;
    __syncthreads();
    float* pb = part + (size_t)blockIdx.x * PSTRIDE;
    if (t < 16) {
        f4 s = (f4){0.f, 0.f, 0.f, 0.f};
#pragma unroll
        for (int q = 0; q < 16; ++q) s += ((f4*)fbuf)[q * 16 + t];
        ((f4*)pb)[t] = s;
    }
    __syncthreads();
    // ---- acc merge: C layout col = lane&15, row = (lane>>4)*4 + reg ----
    float* buf = fbuf + (w & 1) * 4096;
    const int lcol = lane & 15, lrow4 = (lane >> 4) * 4;
    if (w < 2) {
#pragma unroll
        for (int mi = 0; mi < 4; ++mi)
#pragma unroll
            for (int mj = 0; mj < 4; ++mj)
#pragma unroll
                for (int rg = 0; rg < 4; ++rg)
                    buf[(mi * 16 + lrow4 + rg) * 64 + mj * 16 + lcol] = acc[mi][mj][rg];
    }
    __syncthreads();
    if (w >= 2) {
#pragma unroll
        for (int mi = 0; mi < 4; ++mi)
#pragma unroll
            for (int mj = 0; mj < 4; ++mj)
#pragma unroll
                for (int rg = 0; rg < 4; ++rg)
                    buf[(mi * 16 + lrow4 + rg) * 64 + mj * 16 + lcol] += acc[mi][mj][rg];
    }
    __syncthreads();
#pragma unroll
    for (int q = 0; q < 16; ++q) {
        int e = t + q * 256;
        pb[64 + e] = fbuf[e] + fbuf[4096 + e];
    }
}

// ---------------------------------------------------------------------------
// Kernel A2a: stage-1 reduce. GBLK partials -> RGRP group-partials.
// ---------------------------------------------------------------------------
__global__ __launch_bounds__(256) void k_reduce1(const float* __restrict__ part,
                                                 float* __restrict__ part2)
{
    const int gid = blockIdx.x * 256 + threadIdx.x;
    const int grp = blockIdx.y;
    if (gid >= PSTRIDE) return;
    const float* pp = part + (size_t)grp * (GBLK / RGRP) * PSTRIDE + gid;
    float s[8];
#pragma unroll
    for (int j = 0; j < 8; ++j) s[j] = 0.f;
#pragma unroll
    for (int i = 0; i < GBLK / RGRP; i += 8)
#pragma unroll
        for (int j = 0; j < 8; ++j)
            s[j] += pp[(size_t)(i + j) * PSTRIDE];
    part2[(size_t)grp * PSTRIDE + gid] =
        ((s[0] + s[1]) + (s[2] + s[3])) + ((s[4] + s[5]) + (s[6] + s[7]));
}

// ---------------------------------------------------------------------------
// Kernel A2b: stage-2 reduce. RGRP group-partials -> stats[4160]. L2-hot.
// ---------------------------------------------------------------------------
__global__ __launch_bounds__(256) void k_reduce2(const float* __restrict__ part2,
                                                 float* __restrict__ stats)
{
    const int gid = blockIdx.x * 256 + threadIdx.x;
    if (gid >= PSTRIDE) return;
    float s[8];
#pragma unroll
    for (int j = 0; j < 8; ++j) s[j] = 0.f;
#pragma unroll
    for (int i = 0; i < RGRP; i += 8)
#pragma unroll
        for (int j = 0; j < 8; ++j)
            s[j] += part2[(size_t)(i + j) * PSTRIDE + gid];
    stats[gid] = ((s[0] + s[1]) + (s[2] + s[3])) + ((s[4] + s[5]) + (s[6] + s[7]));
}

// ---------------------------------------------------------------------------
// Fallback Gram (atomic) for tiny ws.
// ---------------------------------------------------------------------------
__global__ __launch_bounds__(256) void k_gram_at(const float* __restrict__ feat,
                                                 float* __restrict__ stats)
{
    __shared__ float tile[64 * 64];
    f4* tile4 = (f4*)tile;
    const f4* feat4 = (const f4*)feat;
    const int t = threadIdx.x;
    const int i0 = (t >> 4) << 2;
    const int j0 = (t & 15) << 2;
    float acc[16];
#pragma unroll
    for (int k = 0; k < 16; ++k) acc[k] = 0.f;
    float csum = 0.f;
    for (int c = 0; c < 8; ++c) {
        const int base4 = (blockIdx.x * 512 + c * 64) * 16;
        __syncthreads();
#pragma unroll
        for (int k = 0; k < 4; ++k) tile4[t + k * 256] = feat4[base4 + t + k * 256];
        __syncthreads();
        for (int r = 0; r < 64; ++r) {
            f4 fi = tile4[r * 16 + (i0 >> 2)];
            f4 fj = tile4[r * 16 + (j0 >> 2)];
#pragma unroll
            for (int ii = 0; ii < 4; ++ii)
#pragma unroll
                for (int jj = 0; jj < 4; ++jj)
                    acc[ii * 4 + jj] = fmaf(fi[ii], fj[jj], acc[ii * 4 + jj]);
        }
        if (t < 64) {
            for (int r = 0; r < 64; ++r) csum += tile[r * 64 + t];
        }
    }
#pragma unroll
    for (int ii = 0; ii < 4; ++ii)
#pragma unroll
        for (int jj = 0; jj < 4; ++jj)
            atomicAdd(&stats[64 + (i0 + ii) * 64 + (j0 + jj)], acc[ii * 4 + jj]);
    if (t < 64) atomicAdd(&stats[t], csum);
}

// ---------------------------------------------------------------------------
// Kernel B: per-channel BN scale/shift from Gram + colsum (bias b cancels).
// ---------------------------------------------------------------------------
__global__ __launch_bounds__(64) void k_stats(const float* __restrict__ stats,
                                              const float* __restrict__ W,
                                              const float* __restrict__ gamma,
                                              const float* __restrict__ beta,
                                              float* __restrict__ ST)
{
    const int o = blockIdx.x;
    const int i = threadIdx.x;
    __shared__ float wrow[64];
    wrow[i] = W[o * 64 + i];
    __syncthreads();
    const float* G = stats + 64;
    float inner = 0.f;
    for (int j = 0; j < 64; ++j) inner = fmaf(G[i * 64 + j], wrow[j], inner);
    float qi = inner * wrow[i];
    float cwi = stats[i] * wrow[i];
#pragma unroll
    for (int off = 32; off > 0; off >>= 1) {
        qi += __shfl_down(qi, off);
        cwi += __shfl_down(cwi, off);
    }
    if (i == 0) {
        const double invR = 1.0 / (double)Rr;
        double meanr = (double)cwi * invR;
        double var = (double)qi * invR - meanr * meanr;
        float s = gamma[o] / sqrtf((float)var + EPS);
        ST[o] = s;
        ST[DOUT + o] = beta[o] - (float)meanr * s;
    }
}

// ---------------------------------------------------------------------------
// Kernel C (fused gather+GEMM+max, 32x32x16) v10b -- MAX CONCURRENCY,
// lW staging FIXED (R15: wrote 8-B entries at 16-B-entry addresses with
// c4 in [0,16) -> OOB past the 16 KB lW -> inf. Correct map: f4 covers
// elements c4*4..c4*4+3 = 8-B half (c4&1) of 16-B chunk (c4>>1); write at
// (c4>>1)*2048 + row*16 + (c4&1)*8. 8 chunks x 2048 B = exactly 16 KB.
// Read chunk ks*2+hi covers elements ks*16+hi*8..+8, matching A slices.)
//  * 2048 blocks x 256 thr (4 waves): 8 blocks/CU x 4 waves = 32 waves/CU
//    possible (VGPR <= 64, LDS 16 KB x 8 = 128 KB). 2x concurrency vs v9.
//  * Phases: 4 x 4 batches (8 MB; FETCH volume proved non-binding).
//  * NT loads on A-row gathers (L1 bypass); conflict-free lW reads.
//  * Pre-committed: if k_gmax ~42 us at >=60% occupancy, the random-gather
//    wall is the roofline.
// ---------------------------------------------------------------------------
__global__ __launch_bounds__(256) void k_gmax(const unsigned short* __restrict__ feat16,
                                              const float* __restrict__ W,
                                              const float* __restrict__ ST,
                                              const int* __restrict__ kidx,
                                              const int* __restrict__ fps,
                                              const float* __restrict__ pos,
                                              float* __restrict__ out)
{
    __shared__ char lW[16 * 1024];               // [chunk0..7][row0..127] x 16 B
    const int t = threadIdx.x;
    const f4* W4 = (const f4*)W;
#pragma unroll
    for (int i = 0; i < 8; ++i) {                // 2048 f4 / 256 thr
        int idx = t + i * 256;
        int row = idx >> 4, c4 = idx & 15;       // f4 = elements c4*4..c4*4+3
        f4 v = W4[idx];
        uint2 pk = {cvt2(v[0], v[1]), cvt2(v[2], v[3])};
        *(uint2*)(lW + (c4 >> 1) * 2048 + row * 16 + (c4 & 1) * 8) = pk;
    }

    const int lane = t & 63;
    const int w = t >> 6;                        // 0..3
    const int l31 = lane & 31;
    const int hi = lane >> 5;
    const int bl = blockIdx.x;                   // 0..2047

    float sc[4], tc[4];
#pragma unroll
    for (int cg = 0; cg < 4; ++cg) {
        sc[cg] = ST[cg * 32 + l31];
        tc[cg] = ST[DOUT + cg * 32 + l31];
    }

    // phase ph covers pairs [ph*16384, +16384) = batches 4ph..4ph+3
    int p_next = bl * 8 + w * 2;                 // phase 0 pair base
    int ids_next = __builtin_nontemporal_load(&kidx[p_next * KNN + l31]);

    __syncthreads();                             // lW staged

    bf16x8 A[2][4];
    {
        int bn = p_next >> 12;
        const unsigned short* rp = feat16 + (size_t)bn * Nc * 64 +
                                   (size_t)ids_next * 64 + hi * 8;
#pragma unroll
        for (int ks = 0; ks < 4; ++ks)
            A[0][ks] = __builtin_nontemporal_load((const bf16x8*)(rp + ks * 16));
    }
    int p_cur = p_next;
    p_next += 16384;
    ids_next = __builtin_nontemporal_load(&kidx[p_next * KNN + l31]);

#pragma unroll
    for (int ph = 0; ph < 4; ++ph) {
        const int cur = ph & 1;
        const int pc = p_cur;
        const int batchc = pc >> 12;

        if (ph < 3) {                            // issue next phase's A first
            int bn = p_next >> 12;
            const unsigned short* rp = feat16 + (size_t)bn * Nc * 64 +
                                       (size_t)ids_next * 64 + hi * 8;
#pragma unroll
            for (int ks = 0; ks < 4; ++ks)
                A[cur ^ 1][ks] = __builtin_nontemporal_load((const bf16x8*)(rp + ks * 16));
            p_cur = p_next;
            if (ph < 2) {
                p_next += 16384;
                ids_next = __builtin_nontemporal_load(&kidx[p_next * KNN + l31]);
            }
        }

        if (l31 < 3) {                           // pos_ds gather
            int p = pc + hi;
            int id2 = fps[p];
            __builtin_nontemporal_store(pos[((size_t)batchc * Nc + id2) * 3 + l31],
                                        &out[p * 3 + l31]);
        }

#pragma unroll
        for (int cg = 0; cg < 4; ++cg) {
            const int row = cg * 32 + l31;
            f32x16 acc = {};
            __builtin_amdgcn_s_setprio(1);
#pragma unroll
            for (int ks = 0; ks < 4; ++ks) {
                bf16x8 wfv = *(const bf16x8*)(lW + (ks * 2 + hi) * 2048 + row * 16);
                acc = __builtin_amdgcn_mfma_f32_32x32x16_bf16(A[cur][ks], wfv, acc, 0, 0, 0);
            }
            __builtin_amdgcn_s_setprio(0);
            float vmA = fmaxf(fmaxf(fmaxf(acc[0], acc[1]), fmaxf(acc[2], acc[3])),
                              fmaxf(fmaxf(acc[4], acc[5]), fmaxf(acc[6], acc[7])));
            float vmB = fmaxf(fmaxf(fmaxf(acc[8], acc[9]), fmaxf(acc[10], acc[11])),
                              fmaxf(fmaxf(acc[12], acc[13]), fmaxf(acc[14], acc[15])));
            vmA = fmaxf(vmA, __shfl_xor(vmA, 32));   // other half's 8 neighbor-rows
            vmB = fmaxf(vmB, __shfl_xor(vmB, 32));
            float vsel = hi ? vmB : vmA;             // rows 0-15 = pair pc, 16-31 = pc+1
            __builtin_nontemporal_store(
                fmaxf(fmaf(vsel, sc[cg], tc[cg]), 0.f),
                &out[POS_OUT + (size_t)(pc + hi) * DOUT + cg * 32 + l31]);
        }
    }
}

// ---------------------------------------------------------------------------
// Fallback (ws too small): recompute h at gathered rows (includes pos).
// ---------------------------------------------------------------------------
__global__ __launch_bounds__(128) void k_gather_rc(const float* __restrict__ feat,
                                                   const float* __restrict__ W,
                                                   const float* __restrict__ ST,
                                                   const int* __restrict__ kidx,
                                                   const int* __restrict__ fps,
                                                   const float* __restrict__ pos,
                                                   float* __restrict__ out)
{
    __shared__ float frow[KNN][DIN];
    const int p = blockIdx.x;
    const int o = threadIdx.x;
    const int b = p >> 12;
    const f4* featf = (const f4*)feat;
    f4* frow4 = (f4*)frow;
#pragma unroll
    for (int q = 0; q < 2; ++q) {
        int jj = o + q * 128;
        int row = jj >> 4, i4 = jj & 15;
        int id = kidx[p * KNN + row];
        frow4[jj] = featf[((size_t)b * Nc + id) * 16 + i4];
    }
    __syncthreads();
    float wreg[64];
#pragma unroll
    for (int i4 = 0; i4 < 16; ++i4) {
        f4 wv = ((const f4*)W)[o * 16 + i4];
        wreg[i4 * 4 + 0] = wv[0];
        wreg[i4 * 4 + 1] = wv[1];
        wreg[i4 * 4 + 2] = wv[2];
        wreg[i4 * 4 + 3] = wv[3];
    }
    const float s = ST[o], tt = ST[DOUT + o];
    float vm = 0.f;
    for (int k = 0; k < KNN; ++k) {
        float acc = 0.f;
#pragma unroll
        for (int i = 0; i < 64; ++i) acc = fmaf(frow[k][i], wreg[i], acc);
        vm = fmaxf(vm, fmaf(acc, s, tt));
    }
    out[POS_OUT + (size_t)p * DOUT + o] = vm;
    if (o < 3) {
        int id = fps[p];
        out[p * 3 + o] = pos[((size_t)b * Nc + id) * 3 + o];
    }
}

extern "C" void kernel_launch(void* const* d_in, const int* in_sizes, int n_in,
                              void* d_out, int out_size, void* d_ws, size_t ws_size,
                              hipStream_t stream)
{
    const float* pos   = (const float*)d_in[0];
    const float* feat  = (const float*)d_in[1];
    const int*   fps   = (const int*)d_in[2];
    const int*   kidx  = (const int*)d_in[3];
    const float* W     = (const float*)d_in[4];
    // d_in[5] = bias b: cancels exactly under BatchNorm, unused
    const float* gamma = (const float*)d_in[6];
    const float* beta  = (const float*)d_in[7];
    float* out = (float*)d_out;

    float* stats = (float*)d_ws;                 // [0,4160) colsum+gram
    float* ST = stats + PSTRIDE;                 // s,t (256 floats)
    const size_t F16_OFF = 32768;
    const size_t F16_BYTES = (size_t)Rr * DIN * 2;               // 32 MiB
    unsigned short* feat16 = (unsigned short*)((char*)d_ws + F16_OFF);
    float* part  = (float*)((char*)d_ws + F16_OFF + F16_BYTES);  // 8.5 MB partials
    float* part2 = part + (size_t)GBLK * PSTRIDE;                // 532 KB stage-2
    const size_t need = F16_OFF + F16_BYTES +
                        (size_t)(GBLK + RGRP) * PSTRIDE * 4;

    if (ws_size >= need) {
        k_gram<<<GBLK, 256, 0, stream>>>(feat, feat16, part);
        k_reduce1<<<dim3((PSTRIDE + 255) / 256, RGRP), 256, 0, stream>>>(part, part2);
        k_reduce2<<<(PSTRIDE + 255) / 256, 256, 0, stream>>>(part2, stats);
        k_stats<<<DOUT, 64, 0, stream>>>(stats, W, gamma, beta, ST);
        k_gmax<<<2048, 256, 0, stream>>>(feat16, W, ST, kidx, fps, pos, out);
    } else {
        hipMemsetAsync(d_ws, 0, PSTRIDE * 4, stream);
        k_gram_at<<<512, 256, 0, stream>>>(feat, stats);
        k_stats<<<DOUT, 64, 0, stream>>>(stats, W, gamma, beta, ST);
        k_gather_rc<<<Bc * Mc, 128, 0, stream>>>(feat, W, ST, kidx, fps, pos, out);
    }
}

// Round 17
// 63.482 us; speedup vs baseline: 1.5128x; 1.5128x over previous
//
#include <hip/hip_runtime.h>
#include <hip/hip_bf16.h>
#include <stdint.h>

typedef float f4 __attribute__((ext_vector_type(4)));
typedef float f32x4v __attribute__((ext_vector_type(4)));
typedef float f32x16 __attribute__((ext_vector_type(16)));
typedef short bf16x8 __attribute__((ext_vector_type(8)));
typedef unsigned int u32x2 __attribute__((ext_vector_type(2)));

static constexpr int Bc = 16, Nc = 16384, DIN = 64, DOUT = 128, Mc = 4096, KNN = 16;
static constexpr long Rr = (long)Bc * Nc;        // 262144 rows
static constexpr float EPS = 1e-5f;
static constexpr int POS_OUT = Bc * Mc * 3;      // 196608 floats of pos_ds
static constexpr int GBLK = 512;                 // k_gram blocks (512 rows each)
static constexpr int PSTRIDE = 4160;             // 64 colsum + 4096 gram per partial
static constexpr int RGRP = 32;                  // reduction groups (stage 1)
static constexpr int CG_STRIDE = 8224;           // bytes per 16-chan LDS subtile (+32 pad)

__device__ __forceinline__ uint32_t cvt2(float a, float b) {
    union { __hip_bfloat162 h; uint32_t u; } c;
    c.h = __float22bfloat162_rn(make_float2(a, b));   // v_cvt_pk_bf16_f32
    return c.u;
}

// ---------------------------------------------------------------------------
// Kernel A (MFMA Gram): G = feat^T feat via mfma_f32_16x16x32_bf16 with
// ds_read_b64_tr_b16 fragments (one fragment serves as both A and B).
// Emits feat16 + colsum. 512 blocks x 512 rows. (~HBM floor since R9.)
// ---------------------------------------------------------------------------
__global__ __launch_bounds__(256) void k_gram(const float* __restrict__ feat,
                                              unsigned short* __restrict__ feat16,
                                              float* __restrict__ part)
{
    __shared__ alignas(16) char lds[4 * CG_STRIDE];   // 32896 B; reused as merge buf
    const int t = threadIdx.x;
    const int lane = t & 63;
    const int w = t >> 6;
    const long R0 = (long)blockIdx.x * 512;
    const f4* feat4 = (const f4*)feat;
    const unsigned lds_base = (unsigned)(size_t)&lds[0];

    f32x4v acc[4][4];
#pragma unroll
    for (int mi = 0; mi < 4; ++mi)
#pragma unroll
        for (int mj = 0; mj < 4; ++mj) acc[mi][mj] = (f32x4v){0.f, 0.f, 0.f, 0.f};
    f4 csum = (f4){0.f, 0.f, 0.f, 0.f};

    f4 v[16];
#pragma unroll
    for (int i = 0; i < 16; ++i)                 // preload chunk 0 (coalesced)
        v[i] = feat4[R0 * 16 + t + i * 256];

    const int c4 = t & 15;
    const int cg = c4 >> 2;

    for (int ch = 0; ch < 2; ++ch) {
        // ---- stage: bf16 to LDS subtiles + feat16 global + colsum ----
#pragma unroll
        for (int i = 0; i < 16; ++i) {
            int row = (t + i * 256) >> 4;        // 0..255
            uint2 pk = {cvt2(v[i][0], v[i][1]), cvt2(v[i][2], v[i][3])};
            csum += v[i];
            *(uint2*)(feat16 + (size_t)(R0 + ch * 256 + row) * 64 + c4 * 4) = pk;
            *(uint2*)(lds + cg * CG_STRIDE + row * 32 + (c4 & 3) * 8) = pk;
        }
        __syncthreads();
        if (ch == 0) {                           // preload chunk 1 under compute
#pragma unroll
            for (int i = 0; i < 16; ++i)
                v[i] = feat4[(R0 + 256) * 16 + t + i * 256];
        }
        // ---- compute: wave w owns K-steps 2w, 2w+1 (32 rows each) ----
#pragma unroll
        for (int s = 0; s < 2; ++s) {
            const unsigned base = lds_base + (unsigned)((w * 2 + s) * 32 * 32 + lane * 8);
            u32x2 r0[4], r1[4];
#pragma unroll
            for (int g = 0; g < 4; ++g) {
                unsigned a = base + g * CG_STRIDE;
                asm volatile("ds_read_b64_tr_b16 %0, %2 offset:0\n\t"
                             "ds_read_b64_tr_b16 %1, %2 offset:512"
                             : "=v"(r0[g]), "=v"(r1[g]) : "v"(a));
            }
            asm volatile("s_waitcnt lgkmcnt(0)" ::: "memory");
            __builtin_amdgcn_sched_barrier(0);
            bf16x8 f[4];
#pragma unroll
            for (int g = 0; g < 4; ++g) {
                union { u32x2 p[2]; bf16x8 v8; } u;
                u.p[0] = r0[g]; u.p[1] = r1[g];
                f[g] = u.v8;
            }
#pragma unroll
            for (int mi = 0; mi < 4; ++mi)
#pragma unroll
                for (int mj = 0; mj < 4; ++mj)
                    acc[mi][mj] = __builtin_amdgcn_mfma_f32_16x16x32_bf16(
                        f[mi], f[mj], acc[mi][mj], 0, 0, 0);
        }
        __syncthreads();
    }

    // ---- colsum merge ----
    float* fbuf = (float*)lds;
    ((f4*)fbuf)[t] = csum;
    __syncthreads();
    float* pb = part + (size_t)blockIdx.x * PSTRIDE;
    if (t < 16) {
        f4 s = (f4){0.f, 0.f, 0.f, 0.f};
#pragma unroll
        for (int q = 0; q < 16; ++q) s += ((f4*)fbuf)[q * 16 + t];
        ((f4*)pb)[t] = s;
    }
    __syncthreads();
    // ---- acc merge: C layout col = lane&15, row = (lane>>4)*4 + reg ----
    float* buf = fbuf + (w & 1) * 4096;
    const int lcol = lane & 15, lrow4 = (lane >> 4) * 4;
    if (w < 2) {
#pragma unroll
        for (int mi = 0; mi < 4; ++mi)
#pragma unroll
            for (int mj = 0; mj < 4; ++mj)
#pragma unroll
                for (int rg = 0; rg < 4; ++rg)
                    buf[(mi * 16 + lrow4 + rg) * 64 + mj * 16 + lcol] = acc[mi][mj][rg];
    }
    __syncthreads();
    if (w >= 2) {
#pragma unroll
        for (int mi = 0; mi < 4; ++mi)
#pragma unroll
            for (int mj = 0; mj < 4; ++mj)
#pragma unroll
                for (int rg = 0; rg < 4; ++rg)
                    buf[(mi * 16 + lrow4 + rg) * 64 + mj * 16 + lcol] += acc[mi][mj][rg];
    }
    __syncthreads();
#pragma unroll
    for (int q = 0; q < 16; ++q) {
        int e = t + q * 256;
        pb[64 + e] = fbuf[e] + fbuf[4096 + e];
    }
}

// ---------------------------------------------------------------------------
// Kernel A2a: stage-1 reduce. GBLK partials -> RGRP group-partials.
// ---------------------------------------------------------------------------
__global__ __launch_bounds__(256) void k_reduce1(const float* __restrict__ part,
                                                 float* __restrict__ part2)
{
    const int gid = blockIdx.x * 256 + threadIdx.x;
    const int grp = blockIdx.y;
    if (gid >= PSTRIDE) return;
    const float* pp = part + (size_t)grp * (GBLK / RGRP) * PSTRIDE + gid;
    float s[8];
#pragma unroll
    for (int j = 0; j < 8; ++j) s[j] = 0.f;
#pragma unroll
    for (int i = 0; i < GBLK / RGRP; i += 8)
#pragma unroll
        for (int j = 0; j < 8; ++j)
            s[j] += pp[(size_t)(i + j) * PSTRIDE];
    part2[(size_t)grp * PSTRIDE + gid] =
        ((s[0] + s[1]) + (s[2] + s[3])) + ((s[4] + s[5]) + (s[6] + s[7]));
}

// ---------------------------------------------------------------------------
// Kernel A2b: stage-2 reduce. RGRP group-partials -> stats[4160]. L2-hot.
// ---------------------------------------------------------------------------
__global__ __launch_bounds__(256) void k_reduce2(const float* __restrict__ part2,
                                                 float* __restrict__ stats)
{
    const int gid = blockIdx.x * 256 + threadIdx.x;
    if (gid >= PSTRIDE) return;
    float s[8];
#pragma unroll
    for (int j = 0; j < 8; ++j) s[j] = 0.f;
#pragma unroll
    for (int i = 0; i < RGRP; i += 8)
#pragma unroll
        for (int j = 0; j < 8; ++j)
            s[j] += part2[(size_t)(i + j) * PSTRIDE + gid];
    stats[gid] = ((s[0] + s[1]) + (s[2] + s[3])) + ((s[4] + s[5]) + (s[6] + s[7]));
}

// ---------------------------------------------------------------------------
// Fallback Gram (atomic) for tiny ws.
// ---------------------------------------------------------------------------
__global__ __launch_bounds__(256) void k_gram_at(const float* __restrict__ feat,
                                                 float* __restrict__ stats)
{
    __shared__ float tile[64 * 64];
    f4* tile4 = (f4*)tile;
    const f4* feat4 = (const f4*)feat;
    const int t = threadIdx.x;
    const int i0 = (t >> 4) << 2;
    const int j0 = (t & 15) << 2;
    float acc[16];
#pragma unroll
    for (int k = 0; k < 16; ++k) acc[k] = 0.f;
    float csum = 0.f;
    for (int c = 0; c < 8; ++c) {
        const int base4 = (blockIdx.x * 512 + c * 64) * 16;
        __syncthreads();
#pragma unroll
        for (int k = 0; k < 4; ++k) tile4[t + k * 256] = feat4[base4 + t + k * 256];
        __syncthreads();
        for (int r = 0; r < 64; ++r) {
            f4 fi = tile4[r * 16 + (i0 >> 2)];
            f4 fj = tile4[r * 16 + (j0 >> 2)];
#pragma unroll
            for (int ii = 0; ii < 4; ++ii)
#pragma unroll
                for (int jj = 0; jj < 4; ++jj)
                    acc[ii * 4 + jj] = fmaf(fi[ii], fj[jj], acc[ii * 4 + jj]);
        }
        if (t < 64) {
            for (int r = 0; r < 64; ++r) csum += tile[r * 64 + t];
        }
    }
#pragma unroll
    for (int ii = 0; ii < 4; ++ii)
#pragma unroll
        for (int jj = 0; jj < 4; ++jj)
            atomicAdd(&stats[64 + (i0 + ii) * 64 + (j0 + jj)], acc[ii * 4 + jj]);
    if (t < 64) atomicAdd(&stats[t], csum);
}

// ---------------------------------------------------------------------------
// Kernel B: per-channel BN scale/shift from Gram + colsum (bias b cancels).
// ---------------------------------------------------------------------------
__global__ __launch_bounds__(64) void k_stats(const float* __restrict__ stats,
                                              const float* __restrict__ W,
                                              const float* __restrict__ gamma,
                                              const float* __restrict__ beta,
                                              float* __restrict__ ST)
{
    const int o = blockIdx.x;
    const int i = threadIdx.x;
    __shared__ float wrow[64];
    wrow[i] = W[o * 64 + i];
    __syncthreads();
    const float* G = stats + 64;
    float inner = 0.f;
    for (int j = 0; j < 64; ++j) inner = fmaf(G[i * 64 + j], wrow[j], inner);
    float qi = inner * wrow[i];
    float cwi = stats[i] * wrow[i];
#pragma unroll
    for (int off = 32; off > 0; off >>= 1) {
        qi += __shfl_down(qi, off);
        cwi += __shfl_down(cwi, off);
    }
    if (i == 0) {
        const double invR = 1.0 / (double)Rr;
        double meanr = (double)cwi * invR;
        double var = (double)qi * invR - meanr * meanr;
        float s = gamma[o] / sqrtf((float)var + EPS);
        ST[o] = s;
        ST[DOUT + o] = beta[o] - (float)meanr * s;
    }
}

// ---------------------------------------------------------------------------
// Kernel C (fused gather+GEMM+max, 32x32x16) v9 -- BEST MEASURED (R14,
// total 64.07 us). Reverted after v10b (67 us) regressed. Scorecard over
// seven designs: every lever (ILP, TLP, DS-op count, line-touches, FETCH
// volume, L2 phasing, NT, grid shape) null or worse; duration floors at
// 42-45 us == per-CU random-gather request-path wall (~32 line-lookups/
// pair x 65536 pairs / 256 CU x ~10 cyc). This config: 512 blocks x 512
// thr, 8 time-phases x 2 batches (4 MB L2 working set), LDS-W XOR-
// swizzled, 2-pair/wave via 32-row A, shfl_xor(32) max, A prefetched one
// phase ahead, NT stores.
// ---------------------------------------------------------------------------
__global__ __launch_bounds__(512) void k_gmax(const unsigned short* __restrict__ feat16,
                                              const float* __restrict__ W,
                                              const float* __restrict__ ST,
                                              const int* __restrict__ kidx,
                                              const int* __restrict__ fps,
                                              const float* __restrict__ pos,
                                              float* __restrict__ out)
{
    __shared__ char lW[16 * 1024];               // W bf16 [128][64], XOR-swizzled
    const int t = threadIdx.x;
    const f4* W4 = (const f4*)W;
#pragma unroll
    for (int i = 0; i < 4; ++i) {                // 2048 f4 / 512 thr
        int idx = t + i * 512;
        int row = idx >> 4, c4 = idx & 15;
        f4 v = W4[idx];
        uint2 pk = {cvt2(v[0], v[1]), cvt2(v[2], v[3])};
        *(uint2*)(lW + row * 128 + ((c4 * 8) ^ ((row & 7) << 4))) = pk;
    }

    const int lane = t & 63;
    const int w = t >> 6;                        // 0..7
    const int l31 = lane & 31;
    const int hi = lane >> 5;
    const int bl = blockIdx.x;                   // 0..511

    float sc[4], tc[4];
#pragma unroll
    for (int cg = 0; cg < 4; ++cg) {
        sc[cg] = ST[cg * 32 + l31];
        tc[cg] = ST[DOUT + cg * 32 + l31];
    }

    // phase ph covers global pairs [ph*8192, (ph+1)*8192) = batches {2ph, 2ph+1}
    int p_next = bl * 16 + w * 2;                // phase 0 pair base
    int ids_next = __builtin_nontemporal_load(&kidx[p_next * KNN + l31]);

    __syncthreads();                             // lW staged

    bf16x8 A[2][4];
    {   // issue A for phase 0
        int bn = p_next >> 12;
        const unsigned short* rp = feat16 + (size_t)bn * Nc * 64 +
                                   (size_t)ids_next * 64 + hi * 8;
#pragma unroll
        for (int ks = 0; ks < 4; ++ks) A[0][ks] = *(const bf16x8*)(rp + ks * 16);
    }
    int p_cur = p_next;
    p_next += 8192;
    ids_next = __builtin_nontemporal_load(&kidx[p_next * KNN + l31]);

#pragma unroll
    for (int ph = 0; ph < 8; ++ph) {
        const int cur = ph & 1;
        const int pc = p_cur;
        const int batchc = pc >> 12;

        // issue NEXT phase's A before this phase's MFMAs
        if (ph < 7) {
            int bn = p_next >> 12;
            const unsigned short* rp = feat16 + (size_t)bn * Nc * 64 +
                                       (size_t)ids_next * 64 + hi * 8;
#pragma unroll
            for (int ks = 0; ks < 4; ++ks) A[cur ^ 1][ks] = *(const bf16x8*)(rp + ks * 16);
            p_cur = p_next;
            if (ph < 6) {
                p_next += 8192;
                ids_next = __builtin_nontemporal_load(&kidx[p_next * KNN + l31]);
            }
        }

        // pos_ds gather (independent)
        if (l31 < 3) {
            int p = pc + hi;
            int id2 = fps[p];
            __builtin_nontemporal_store(pos[((size_t)batchc * Nc + id2) * 3 + l31],
                                        &out[p * 3 + l31]);
        }

        // compute on A[cur]
#pragma unroll
        for (int cg = 0; cg < 4; ++cg) {
            const int row = cg * 32 + l31;
            f32x16 acc = {};
            __builtin_amdgcn_s_setprio(1);
#pragma unroll
            for (int ks = 0; ks < 4; ++ks) {
                bf16x8 wfv = *(const bf16x8*)(lW + row * 128 +
                                              ((ks * 32 + hi * 16) ^ ((row & 7) << 4)));
                acc = __builtin_amdgcn_mfma_f32_32x32x16_bf16(A[cur][ks], wfv, acc, 0, 0, 0);
            }
            __builtin_amdgcn_s_setprio(0);
            float vmA = fmaxf(fmaxf(fmaxf(acc[0], acc[1]), fmaxf(acc[2], acc[3])),
                              fmaxf(fmaxf(acc[4], acc[5]), fmaxf(acc[6], acc[7])));
            float vmB = fmaxf(fmaxf(fmaxf(acc[8], acc[9]), fmaxf(acc[10], acc[11])),
                              fmaxf(fmaxf(acc[12], acc[13]), fmaxf(acc[14], acc[15])));
            vmA = fmaxf(vmA, __shfl_xor(vmA, 32));   // other half's 8 neighbor-rows
            vmB = fmaxf(vmB, __shfl_xor(vmB, 32));
            float vsel = hi ? vmB : vmA;             // rows 0-15 = pair pc, 16-31 = pc+1
            __builtin_nontemporal_store(
                fmaxf(fmaf(vsel, sc[cg], tc[cg]), 0.f),
                &out[POS_OUT + (size_t)(pc + hi) * DOUT + cg * 32 + l31]);
        }
    }
}

// ---------------------------------------------------------------------------
// Fallback (ws too small): recompute h at gathered rows (includes pos).
// ---------------------------------------------------------------------------
__global__ __launch_bounds__(128) void k_gather_rc(const float* __restrict__ feat,
                                                   const float* __restrict__ W,
                                                   const float* __restrict__ ST,
                                                   const int* __restrict__ kidx,
                                                   const int* __restrict__ fps,
                                                   const float* __restrict__ pos,
                                                   float* __restrict__ out)
{
    __shared__ float frow[KNN][DIN];
    const int p = blockIdx.x;
    const int o = threadIdx.x;
    const int b = p >> 12;
    const f4* featf = (const f4*)feat;
    f4* frow4 = (f4*)frow;
#pragma unroll
    for (int q = 0; q < 2; ++q) {
        int jj = o + q * 128;
        int row = jj >> 4, i4 = jj & 15;
        int id = kidx[p * KNN + row];
        frow4[jj] = featf[((size_t)b * Nc + id) * 16 + i4];
    }
    __syncthreads();
    float wreg[64];
#pragma unroll
    for (int i4 = 0; i4 < 16; ++i4) {
        f4 wv = ((const f4*)W)[o * 16 + i4];
        wreg[i4 * 4 + 0] = wv[0];
        wreg[i4 * 4 + 1] = wv[1];
        wreg[i4 * 4 + 2] = wv[2];
        wreg[i4 * 4 + 3] = wv[3];
    }
    const float s = ST[o], tt = ST[DOUT + o];
    float vm = 0.f;
    for (int k = 0; k < KNN; ++k) {
        float acc = 0.f;
#pragma unroll
        for (int i = 0; i < 64; ++i) acc = fmaf(frow[k][i], wreg[i], acc);
        vm = fmaxf(vm, fmaf(acc, s, tt));
    }
    out[POS_OUT + (size_t)p * DOUT + o] = vm;
    if (o < 3) {
        int id = fps[p];
        out[p * 3 + o] = pos[((size_t)b * Nc + id) * 3 + o];
    }
}

extern "C" void kernel_launch(void* const* d_in, const int* in_sizes, int n_in,
                              void* d_out, int out_size, void* d_ws, size_t ws_size,
                              hipStream_t stream)
{
    const float* pos   = (const float*)d_in[0];
    const float* feat  = (const float*)d_in[1];
    const int*   fps   = (const int*)d_in[2];
    const int*   kidx  = (const int*)d_in[3];
    const float* W     = (const float*)d_in[4];
    // d_in[5] = bias b: cancels exactly under BatchNorm, unused
    const float* gamma = (const float*)d_in[6];
    const float* beta  = (const float*)d_in[7];
    float* out = (float*)d_out;

    float* stats = (float*)d_ws;                 // [0,4160) colsum+gram
    float* ST = stats + PSTRIDE;                 // s,t (256 floats)
    const size_t F16_OFF = 32768;
    const size_t F16_BYTES = (size_t)Rr * DIN * 2;               // 32 MiB
    unsigned short* feat16 = (unsigned short*)((char*)d_ws + F16_OFF);
    float* part  = (float*)((char*)d_ws + F16_OFF + F16_BYTES);  // 8.5 MB partials
    float* part2 = part + (size_t)GBLK * PSTRIDE;                // 532 KB stage-2
    const size_t need = F16_OFF + F16_BYTES +
                        (size_t)(GBLK + RGRP) * PSTRIDE * 4;

    if (ws_size >= need) {
        k_gram<<<GBLK, 256, 0, stream>>>(feat, feat16, part);
        k_reduce1<<<dim3((PSTRIDE + 255) / 256, RGRP), 256, 0, stream>>>(part, part2);
        k_reduce2<<<(PSTRIDE + 255) / 256, 256, 0, stream>>>(part2, stats);
        k_stats<<<DOUT, 64, 0, stream>>>(stats, W, gamma, beta, ST);
        k_gmax<<<512, 512, 0, stream>>>(feat16, W, ST, kidx, fps, pos, out);
    } else {
        hipMemsetAsync(d_ws, 0, PSTRIDE * 4, stream);
        k_gram_at<<<512, 256, 0, stream>>>(feat, stats);
        k_stats<<<DOUT, 64, 0, stream>>>(stats, W, gamma, beta, ST);
        k_gather_rc<<<Bc * Mc, 128, 0, stream>>>(feat, W, ST, kidx, fps, pos, out);
    }
}